// Round 1
// baseline (3355.018 us; speedup 1.0000x reference)
//
#include <hip/hip_runtime.h>
#include <math.h>

#define NNODES 10000
#define NEDGES 40000
#define DIM 64
#define MC 4160  // 4096 h1-contraction cols + 64 bias cols

__device__ __forceinline__ float sigmoidf_(float x) { return 1.0f / (1.0f + expf(-x)); }

// out0 = relu(x @ lin0_w.T + lin0_b)   [N,64]
__global__ __launch_bounds__(256) void k_node_init(const float* __restrict__ x,
                                                   const float* __restrict__ w,
                                                   const float* __restrict__ b,
                                                   float* __restrict__ out) {
    int idx = blockIdx.x * 256 + threadIdx.x;
    if (idx >= NNODES * 64) return;
    int n = idx >> 6, d = idx & 63;
    float a = b[d];
    a += x[n * 3 + 0] * w[d * 3 + 0];
    a += x[n * 3 + 1] * w[d * 3 + 1];
    a += x[n * 3 + 2] * w[d * 3 + 2];
    out[idx] = fmaxf(a, 0.0f);
}

// h1 = relu(edge_attr @ em1_w.T + em1_b)   [E,64]
__global__ __launch_bounds__(256) void k_h1(const float* __restrict__ ea,
                                            const float* __restrict__ w,
                                            const float* __restrict__ b,
                                            float* __restrict__ h1) {
    int idx = blockIdx.x * 256 + threadIdx.x;
    if (idx >= NEDGES * 64) return;
    int e = idx >> 6, d = idx & 63;
    float a = b[d];
#pragma unroll
    for (int j = 0; j < 7; ++j) a += ea[e * 7 + j] * w[d * 7 + j];
    h1[idx] = fmaxf(a, 0.0f);
}

// W2[i, o*64+k] = em2_w[(i*64+o)*64 + k];  W2[i, 4096+o] = em2_b[i*64+o]
__global__ __launch_bounds__(256) void k_w2(const float* __restrict__ em2_w,
                                            const float* __restrict__ em2_b,
                                            float* __restrict__ W2) {
    int idx = blockIdx.x * 256 + threadIdx.x;
    if (idx >= 64 * MC) return;
    int i = idx / MC, c = idx % MC;
    float v;
    if (c < 4096) {
        int o = c >> 6, k = c & 63;
        v = em2_w[((size_t)(i * 64 + o)) * 64 + k];
    } else {
        v = em2_b[i * 64 + (c - 4096)];
    }
    W2[idx] = v;
}

__global__ __launch_bounds__(256) void k_zero(float* __restrict__ p, size_t n) {
    size_t i = (size_t)blockIdx.x * 256 + threadIdx.x;
    if (i < n) p[i] = 0.0f;
}

__global__ __launch_bounds__(256) void k_deg(const int* __restrict__ ei, float* __restrict__ deg) {
    int e = blockIdx.x * 256 + threadIdx.x;
    if (e < NEDGES) atomicAdd(&deg[ei[NEDGES + e]], 1.0f);
}

__global__ __launch_bounds__(256) void k_invdeg(const float* __restrict__ deg, float* __restrict__ inv) {
    int n = blockIdx.x * 256 + threadIdx.x;
    if (n < NNODES) {
        float dg = deg[n];
        inv[n] = dg > 0.0f ? 1.0f / dg : 0.0f;
    }
}

// C[nrows, ncols] = A[nrows,64] @ B[64, ncols], 64x64 tiles, 4x4 per thread
__global__ __launch_bounds__(256) void k_gemm(const float* __restrict__ A,
                                              const float* __restrict__ B,
                                              float* __restrict__ C,
                                              int nrows, int ncols) {
    __shared__ float As[64][68];  // As[k][row]
    __shared__ float Bs[64][68];  // Bs[k][col]
    const int tid = threadIdx.x;
    const int row0 = blockIdx.y * 64;
    const int col0 = blockIdx.x * 64;
#pragma unroll
    for (int j = 0; j < 16; ++j) {
        int idx = tid + 256 * j;
        int i = idx >> 6, k = idx & 63;
        int r = row0 + i;
        As[k][i] = (r < nrows) ? A[(size_t)r * 64 + k] : 0.0f;
        Bs[i][k] = B[(size_t)i * ncols + col0 + k];  // i=k-index, k=col offset here
    }
    __syncthreads();
    const int tx = tid & 15, ty = tid >> 4;
    const int r0 = ty * 4, c0 = tx * 4;
    float acc[4][4] = {{0.f}};
#pragma unroll
    for (int k = 0; k < 64; ++k) {
        float4 av = *reinterpret_cast<const float4*>(&As[k][r0]);
        float4 bv = *reinterpret_cast<const float4*>(&Bs[k][c0]);
        float a[4] = {av.x, av.y, av.z, av.w};
        float b[4] = {bv.x, bv.y, bv.z, bv.w};
#pragma unroll
        for (int i = 0; i < 4; ++i)
#pragma unroll
            for (int jj = 0; jj < 4; ++jj) acc[i][jj] += a[i] * b[jj];
    }
#pragma unroll
    for (int i = 0; i < 4; ++i) {
        int r = row0 + r0 + i;
        if (r < nrows) {
            float4 v = make_float4(acc[i][0], acc[i][1], acc[i][2], acc[i][3]);
            *reinterpret_cast<float4*>(&C[(size_t)r * ncols + col0 + c0]) = v;
        }
    }
}

// per-edge: msg[e,o] = M[s,4096+o] + sum_k h1[e,k]*M[s,o*64+k]; atomic scatter to agg[dst]
__global__ __launch_bounds__(64) void k_msg(const float* __restrict__ M,
                                            const float* __restrict__ h1,
                                            const int* __restrict__ ei,
                                            float* __restrict__ agg) {
    __shared__ float hs[64];
    const int e = blockIdx.x;
    const int o = threadIdx.x;
    const int s = ei[e];
    const int d = ei[NEDGES + e];
    hs[o] = h1[(size_t)e * 64 + o];
    __syncthreads();
    const float* mrow = M + (size_t)s * MC;
    float acc = mrow[4096 + o];
    const float4* mv = reinterpret_cast<const float4*>(mrow + o * 64);
    const float4* hv = reinterpret_cast<const float4*>(hs);
#pragma unroll
    for (int k = 0; k < 16; ++k) {
        float4 m4 = mv[k], h4 = hv[k];
        acc += m4.x * h4.x + m4.y * h4.y + m4.z * h4.z + m4.w * h4.w;
    }
    atomicAdd(&agg[(size_t)d * 64 + o], acc);
}

// fused: m = relu(out@root_w + agg*inv_deg + conv_b); GRU update; out = h_new. 4 nodes/block.
__global__ __launch_bounds__(256) void k_node(const float* __restrict__ agg,
                                              const float* __restrict__ invdeg,
                                              const float* __restrict__ root_w,
                                              const float* __restrict__ conv_b,
                                              const float* __restrict__ wih,
                                              const float* __restrict__ whh,
                                              const float* __restrict__ bih,
                                              const float* __restrict__ bhh,
                                              float* __restrict__ out) {
    __shared__ float wihT[64 * 193];  // [i][j], padded stride 193
    __shared__ float whhT[64 * 193];
    __shared__ float ho[4][64];
    __shared__ float ms[4][64];
    const int tid = threadIdx.x;
#pragma unroll
    for (int it = 0; it < 48; ++it) {  // 192*64 / 256
        int idx = tid + 256 * it;
        int j = idx >> 6, i = idx & 63;
        wihT[i * 193 + j] = wih[idx];
        whhT[i * 193 + j] = whh[idx];
    }
    const int ln = tid >> 6;
    const int d = tid & 63;
    const int n = blockIdx.x * 4 + ln;
    ho[ln][d] = out[(size_t)n * 64 + d];
    __syncthreads();
    float acc = agg[(size_t)n * 64 + d] * invdeg[n] + conv_b[d];
#pragma unroll
    for (int i = 0; i < 64; ++i) acc += ho[ln][i] * root_w[i * 64 + d];
    float mval = fmaxf(acc, 0.0f);
    ms[ln][d] = mval;
    __syncthreads();
    float gi[3], gh[3];
#pragma unroll
    for (int g = 0; g < 3; ++g) {
        float s1 = bih[g * 64 + d], s2 = bhh[g * 64 + d];
#pragma unroll
        for (int i = 0; i < 64; ++i) {
            s1 += ms[ln][i] * wihT[i * 193 + g * 64 + d];
            s2 += ho[ln][i] * whhT[i * 193 + g * 64 + d];
        }
        gi[g] = s1;
        gh[g] = s2;
    }
    float r = sigmoidf_(gi[0] + gh[0]);
    float z = sigmoidf_(gi[1] + gh[1]);
    float nn = tanhf(gi[2] + r * gh[2]);
    out[(size_t)n * 64 + d] = (1.0f - z) * nn + z * ho[ln][d];
}

// Set2Set LSTM step (1 block). iter>0: q_star tail = r/S from prev attention.
__global__ __launch_bounds__(256) void k_lstm(const float* __restrict__ wih,
                                              const float* __restrict__ whh,
                                              const float* __restrict__ bih,
                                              const float* __restrict__ bhh,
                                              float* __restrict__ hl,
                                              float* __restrict__ cl,
                                              float* __restrict__ r_vec,
                                              float* __restrict__ S,
                                              int iter) {
    __shared__ float qs[128];
    __shared__ float gs[256];
    int tid = threadIdx.x;
    if (tid < 64) qs[tid] = hl[tid];
    else if (tid < 128) qs[tid] = (iter > 0) ? r_vec[tid - 64] / S[0] : 0.0f;
    __syncthreads();
    float g = bih[tid] + bhh[tid];
    for (int k = 0; k < 128; ++k) g += qs[k] * wih[tid * 128 + k];
    for (int k = 0; k < 64; ++k) g += qs[k] * whh[tid * 64 + k];
    gs[tid] = g;
    __syncthreads();
    if (tid < 64) {
        float ig = sigmoidf_(gs[tid]);
        float fg = sigmoidf_(gs[64 + tid]);
        float gg = tanhf(gs[128 + tid]);
        float og = sigmoidf_(gs[192 + tid]);
        float c = fg * cl[tid] + ig * gg;
        cl[tid] = c;
        hl[tid] = og * tanhf(c);
        r_vec[tid] = 0.0f;  // reset for upcoming attention pass
        if (tid == 0) S[0] = 0.0f;
    }
}

// attention logits + exp + global sum (no max-sub: |h|<=~4, |q|<=1 -> e bounded ~<<88)
__global__ __launch_bounds__(256) void k_att1(const float* __restrict__ out,
                                              const float* __restrict__ q,
                                              float* __restrict__ e_att,
                                              float* __restrict__ S) {
    __shared__ float qs[64];
    __shared__ float red[256];
    int tid = threadIdx.x;
    if (tid < 64) qs[tid] = q[tid];
    __syncthreads();
    int n = blockIdx.x * 256 + tid;
    float w = 0.0f;
    if (n < NNODES) {
        const float4* row = reinterpret_cast<const float4*>(out + (size_t)n * 64);
        const float4* qv = reinterpret_cast<const float4*>(qs);
        float e = 0.0f;
#pragma unroll
        for (int k = 0; k < 16; ++k) {
            float4 a = row[k], b = qv[k];
            e += a.x * b.x + a.y * b.y + a.z * b.z + a.w * b.w;
        }
        w = expf(e);
        e_att[n] = w;
    }
    red[tid] = w;
    __syncthreads();
    for (int s = 128; s > 0; s >>= 1) {
        if (tid < s) red[tid] += red[tid + s];
        __syncthreads();
    }
    if (tid == 0) atomicAdd(S, red[0]);
}

// weighted readout: r_vec[d] += sum_n e_att[n]*out[n,d]  (divide by S deferred)
__global__ __launch_bounds__(64) void k_att2(const float* __restrict__ out,
                                             const float* __restrict__ e_att,
                                             float* __restrict__ r_vec) {
    const int d = threadIdx.x;
    const int start = blockIdx.x * 100;
    const int end = (start + 100 < NNODES) ? start + 100 : NNODES;
    float acc = 0.0f;
    for (int n = start; n < end; ++n) acc += e_att[n] * out[(size_t)n * 64 + d];
    atomicAdd(&r_vec[d], acc);
}

__global__ __launch_bounds__(128) void k_out(const float* __restrict__ hl,
                                             const float* __restrict__ r_vec,
                                             const float* __restrict__ S,
                                             const float* __restrict__ lin1_w,
                                             const float* __restrict__ lin1_b,
                                             const float* __restrict__ lin3_w,
                                             const float* __restrict__ lin3_b,
                                             float* __restrict__ dout) {
    __shared__ float qs[128];
    __shared__ float hs[64];
    int tid = threadIdx.x;
    qs[tid] = (tid < 64) ? hl[tid] : r_vec[tid - 64] / S[0];
    __syncthreads();
    if (tid < 64) {
        float a = lin1_b[tid];
        for (int k = 0; k < 128; ++k) a += qs[k] * lin1_w[tid * 128 + k];
        hs[tid] = fmaxf(a, 0.0f);
    }
    __syncthreads();
    if (tid == 0) {
        float a = lin3_b[0];
        for (int k = 0; k < 64; ++k) a += hs[k] * lin3_w[k];
        dout[0] = a;
    }
}

extern "C" void kernel_launch(void* const* d_in, const int* in_sizes, int n_in,
                              void* d_out, int out_size, void* d_ws, size_t ws_size,
                              hipStream_t stream) {
    const float* x         = (const float*)d_in[0];
    const float* edge_attr = (const float*)d_in[1];
    const int*   ei        = (const int*)d_in[2];
    const float* lin0_w    = (const float*)d_in[4];
    const float* lin0_b    = (const float*)d_in[5];
    const float* em1_w     = (const float*)d_in[6];
    const float* em1_b     = (const float*)d_in[7];
    const float* em2_w     = (const float*)d_in[8];
    const float* em2_b     = (const float*)d_in[9];
    const float* root_w    = (const float*)d_in[10];
    const float* conv_b    = (const float*)d_in[11];
    const float* gru_wih   = (const float*)d_in[12];
    const float* gru_whh   = (const float*)d_in[13];
    const float* gru_bih   = (const float*)d_in[14];
    const float* gru_bhh   = (const float*)d_in[15];
    const float* lstm_wih  = (const float*)d_in[16];
    const float* lstm_whh  = (const float*)d_in[17];
    const float* lstm_bih  = (const float*)d_in[18];
    const float* lstm_bhh  = (const float*)d_in[19];
    const float* lin1_w    = (const float*)d_in[20];
    const float* lin1_b    = (const float*)d_in[21];
    const float* lin3_w    = (const float*)d_in[22];
    const float* lin3_b    = (const float*)d_in[23];

    float* ws = (float*)d_ws;
    size_t off = 0;
    float* h1    = ws + off; off += (size_t)NEDGES * 64;   // 2,560,000
    float* W2    = ws + off; off += (size_t)64 * MC;       //   266,240
    float* outb  = ws + off; off += (size_t)NNODES * 64;   //   640,000
    float* agg   = ws + off; off += (size_t)NNODES * 64;   //   640,000
    float* deg   = ws + off; off += NNODES;
    float* invd  = ws + off; off += NNODES;
    float* e_att = ws + off; off += NNODES;
    float* r_vec = ws + off; off += 64;  // contiguous s2s state: r_vec, hl, cl, S
    float* hl    = ws + off; off += 64;
    float* cl    = ws + off; off += 64;
    float* S     = ws + off; off += 1;
    off = (off + 15) & ~((size_t)15);
    float* M     = ws + off; off += (size_t)NNODES * MC;   // 41,600,000 (~183 MB total)

    k_node_init<<<2500, 256, 0, stream>>>(x, lin0_w, lin0_b, outb);
    k_h1<<<10000, 256, 0, stream>>>(edge_attr, em1_w, em1_b, h1);
    k_w2<<<(64 * MC + 255) / 256, 256, 0, stream>>>(em2_w, em2_b, W2);
    k_zero<<<40, 256, 0, stream>>>(deg, NNODES);
    k_deg<<<(NEDGES + 255) / 256, 256, 0, stream>>>(ei, deg);
    k_invdeg<<<40, 256, 0, stream>>>(deg, invd);

    for (int t = 0; t < 6; ++t) {
        k_zero<<<2500, 256, 0, stream>>>(agg, (size_t)NNODES * 64);
        k_gemm<<<dim3(65, 157), 256, 0, stream>>>(outb, W2, M, NNODES, MC);
        k_msg<<<NEDGES, 64, 0, stream>>>(M, h1, ei, agg);
        k_node<<<2500, 256, 0, stream>>>(agg, invd, root_w, conv_b, gru_wih, gru_whh,
                                         gru_bih, gru_bhh, outb);
    }

    k_zero<<<1, 256, 0, stream>>>(r_vec, 64 + 64 + 64 + 1);  // r_vec, hl, cl, S
    for (int it = 0; it < 6; ++it) {
        k_lstm<<<1, 256, 0, stream>>>(lstm_wih, lstm_whh, lstm_bih, lstm_bhh, hl, cl, r_vec, S, it);
        k_att1<<<40, 256, 0, stream>>>(outb, hl, e_att, S);
        k_att2<<<100, 64, 0, stream>>>(outb, e_att, r_vec);
    }
    k_out<<<1, 128, 0, stream>>>(hl, r_vec, S, lin1_w, lin1_b, lin3_w, lin3_b, (float*)d_out);
}

// Round 2
// 1767.677 us; speedup vs baseline: 1.8980x; 1.8980x over previous
//
#include <hip/hip_runtime.h>
#include <math.h>

#define NNODES 10000
#define NEDGES 40000
#define DIM 64
#define MC 4160  // 4096 h1-contraction cols + 64 bias cols

__device__ __forceinline__ float sigmoidf_(float x) { return 1.0f / (1.0f + expf(-x)); }

// out0 = relu(x @ lin0_w.T + lin0_b)   [N,64] ; also writes transposed copy
__global__ __launch_bounds__(256) void k_node_init(const float* __restrict__ x,
                                                   const float* __restrict__ w,
                                                   const float* __restrict__ b,
                                                   float* __restrict__ out,
                                                   float* __restrict__ outT) {
    int idx = blockIdx.x * 256 + threadIdx.x;
    if (idx >= NNODES * 64) return;
    int n = idx >> 6, d = idx & 63;
    float a = b[d];
    a += x[n * 3 + 0] * w[d * 3 + 0];
    a += x[n * 3 + 1] * w[d * 3 + 1];
    a += x[n * 3 + 2] * w[d * 3 + 2];
    float v = fmaxf(a, 0.0f);
    out[idx] = v;
    outT[(size_t)d * NNODES + n] = v;
}

// h1 = relu(edge_attr @ em1_w.T + em1_b)   [E,64]
__global__ __launch_bounds__(256) void k_h1(const float* __restrict__ ea,
                                            const float* __restrict__ w,
                                            const float* __restrict__ b,
                                            float* __restrict__ h1) {
    int idx = blockIdx.x * 256 + threadIdx.x;
    if (idx >= NEDGES * 64) return;
    int e = idx >> 6, d = idx & 63;
    float a = b[d];
#pragma unroll
    for (int j = 0; j < 7; ++j) a += ea[e * 7 + j] * w[d * 7 + j];
    h1[idx] = fmaxf(a, 0.0f);
}

// W2[i, o*64+k] = em2_w[(i*64+o)*64 + k];  W2[i, 4096+o] = em2_b[i*64+o]
__global__ __launch_bounds__(256) void k_w2(const float* __restrict__ em2_w,
                                            const float* __restrict__ em2_b,
                                            float* __restrict__ W2) {
    int idx = blockIdx.x * 256 + threadIdx.x;
    if (idx >= 64 * MC) return;
    int i = idx / MC, c = idx % MC;
    float v;
    if (c < 4096) {
        int o = c >> 6, k = c & 63;
        v = em2_w[((size_t)(i * 64 + o)) * 64 + k];
    } else {
        v = em2_b[i * 64 + (c - 4096)];
    }
    W2[idx] = v;
}

__global__ __launch_bounds__(256) void k_zero(float* __restrict__ p, size_t n) {
    size_t i = (size_t)blockIdx.x * 256 + threadIdx.x;
    if (i < n) p[i] = 0.0f;
}

__global__ __launch_bounds__(256) void k_deg(const int* __restrict__ ei, float* __restrict__ deg) {
    int e = blockIdx.x * 256 + threadIdx.x;
    if (e < NEDGES) atomicAdd(&deg[ei[NEDGES + e]], 1.0f);
}

__global__ __launch_bounds__(256) void k_invdeg(const float* __restrict__ deg, float* __restrict__ inv) {
    int n = blockIdx.x * 256 + threadIdx.x;
    if (n < NNODES) {
        float dg = deg[n];
        inv[n] = dg > 0.0f ? 1.0f / dg : 0.0f;
    }
}

// M[N, MC] = outT^T @ W2.  AT = outT [64][N] (k-major), B = W2 [64][MC].
// 128 rows x 64 cols per block; 256 threads; 8x4 per thread.
__global__ __launch_bounds__(256) void k_gemm(const float* __restrict__ AT,
                                              const float* __restrict__ B,
                                              float* __restrict__ C) {
    __shared__ float As[64][136];  // [k][row], pad 8
    __shared__ float Bs[64][68];   // [k][col], pad 4
    const int tid = threadIdx.x;
    const int col0 = blockIdx.x * 64;
    const int row0 = blockIdx.y * 128;
    // stage A: 64 k x 128 rows, coalesced float4 from transposed layout (no LDS transpose)
#pragma unroll
    for (int j = 0; j < 8; ++j) {
        int idx = tid + 256 * j;       // 0..2047
        int k = idx >> 5;              // 0..63
        int r4 = (idx & 31) * 4;       // 0..124
        int r = row0 + r4;
        float4 v;
        if (r + 3 < NNODES) {
            v = *reinterpret_cast<const float4*>(&AT[(size_t)k * NNODES + r]);
        } else {
            v.x = (r + 0 < NNODES) ? AT[(size_t)k * NNODES + r + 0] : 0.0f;
            v.y = (r + 1 < NNODES) ? AT[(size_t)k * NNODES + r + 1] : 0.0f;
            v.z = (r + 2 < NNODES) ? AT[(size_t)k * NNODES + r + 2] : 0.0f;
            v.w = 0.0f;
        }
        *reinterpret_cast<float4*>(&As[k][r4]) = v;
    }
#pragma unroll
    for (int j = 0; j < 4; ++j) {
        int idx = tid + 256 * j;       // 0..1023
        int k = idx >> 4;              // 0..63
        int c4 = (idx & 15) * 4;       // 0..60
        float4 v = *reinterpret_cast<const float4*>(&B[(size_t)k * MC + col0 + c4]);
        *reinterpret_cast<float4*>(&Bs[k][c4]) = v;
    }
    __syncthreads();
    const int tx = tid & 15, ty = tid >> 4;
    const int r0 = ty * 8, c0 = tx * 4;
    float acc[8][4];
#pragma unroll
    for (int i = 0; i < 8; ++i)
#pragma unroll
        for (int j = 0; j < 4; ++j) acc[i][j] = 0.0f;
#pragma unroll 4
    for (int k = 0; k < 64; ++k) {
        float4 b4 = *reinterpret_cast<const float4*>(&Bs[k][c0]);
        float4 a0 = *reinterpret_cast<const float4*>(&As[k][r0]);
        float4 a1 = *reinterpret_cast<const float4*>(&As[k][r0 + 4]);
        float a[8] = {a0.x, a0.y, a0.z, a0.w, a1.x, a1.y, a1.z, a1.w};
        float b[4] = {b4.x, b4.y, b4.z, b4.w};
#pragma unroll
        for (int i = 0; i < 8; ++i)
#pragma unroll
            for (int j = 0; j < 4; ++j) acc[i][j] += a[i] * b[j];
    }
#pragma unroll
    for (int i = 0; i < 8; ++i) {
        int r = row0 + r0 + i;
        if (r < NNODES) {
            *reinterpret_cast<float4*>(&C[(size_t)r * MC + col0 + c0]) =
                make_float4(acc[i][0], acc[i][1], acc[i][2], acc[i][3]);
        }
    }
}

// per-edge: msg[e,o] = M[s,4096+o] + sum_k h1[e,k]*M[s,o*64+k]; atomic scatter to agg[dst]
// 4 edges per 256-thread block
__global__ __launch_bounds__(256) void k_msg(const float* __restrict__ M,
                                             const float* __restrict__ h1,
                                             const int* __restrict__ ei,
                                             float* __restrict__ agg) {
    __shared__ float hs[4][64];
    const int le = threadIdx.x >> 6;
    const int o = threadIdx.x & 63;
    const int e = blockIdx.x * 4 + le;
    const int s = ei[e];
    const int d = ei[NEDGES + e];
    hs[le][o] = h1[(size_t)e * 64 + o];
    __syncthreads();
    const float* mrow = M + (size_t)s * MC;
    float acc = mrow[4096 + o];
    const float4* mv = reinterpret_cast<const float4*>(mrow + o * 64);
    const float4* hv = reinterpret_cast<const float4*>(hs[le]);
#pragma unroll
    for (int k = 0; k < 16; ++k) {
        float4 m4 = mv[k], h4 = hv[k];
        acc += m4.x * h4.x + m4.y * h4.y + m4.z * h4.z + m4.w * h4.w;
    }
    atomicAdd(&agg[(size_t)d * 64 + o], acc);
}

// fused conv-epilogue + GRU. Grid-stride over 4-node tiles; weights staged ONCE per block.
__global__ __launch_bounds__(256) void k_node(const float* __restrict__ agg,
                                              const float* __restrict__ invdeg,
                                              const float* __restrict__ root_w,
                                              const float* __restrict__ conv_b,
                                              const float* __restrict__ wih,
                                              const float* __restrict__ whh,
                                              const float* __restrict__ bih,
                                              const float* __restrict__ bhh,
                                              float* __restrict__ out,
                                              float* __restrict__ outT) {
    __shared__ float wihT[64 * 193];  // [i][j], padded stride 193
    __shared__ float whhT[64 * 193];
    __shared__ float rws[64][65];     // root_w [i][d]
    __shared__ float ho[4][64];
    __shared__ float ms[4][64];
    const int tid = threadIdx.x;
#pragma unroll
    for (int it = 0; it < 48; ++it) {  // 192*64 / 256
        int idx = tid + 256 * it;
        int j = idx >> 6, i = idx & 63;
        wihT[i * 193 + j] = wih[idx];
        whhT[i * 193 + j] = whh[idx];
    }
#pragma unroll
    for (int it = 0; it < 16; ++it) {  // 64*64 / 256
        int idx = tid + 256 * it;
        rws[idx >> 6][idx & 63] = root_w[idx];
    }
    const int ln = tid >> 6;
    const int d = tid & 63;
    const float cb = conv_b[d];
    const float b0 = bih[d] , bh0 = bhh[d];
    const float b1 = bih[64 + d], bh1 = bhh[64 + d];
    const float b2 = bih[128 + d], bh2 = bhh[128 + d];
    __syncthreads();
    for (int tile = blockIdx.x; tile < NNODES / 4; tile += gridDim.x) {
        const int n = tile * 4 + ln;
        ho[ln][d] = out[(size_t)n * 64 + d];
        __syncthreads();
        float acc = agg[(size_t)n * 64 + d] * invdeg[n] + cb;
#pragma unroll
        for (int i = 0; i < 64; ++i) acc += ho[ln][i] * rws[i][d];
        ms[ln][d] = fmaxf(acc, 0.0f);
        __syncthreads();
        float s0 = b0, s1 = b1, s2 = b2;
        float t0 = bh0, t1 = bh1, t2 = bh2;
#pragma unroll
        for (int i = 0; i < 64; ++i) {
            float mi = ms[ln][i], hi = ho[ln][i];
            s0 += mi * wihT[i * 193 + d];
            s1 += mi * wihT[i * 193 + 64 + d];
            s2 += mi * wihT[i * 193 + 128 + d];
            t0 += hi * whhT[i * 193 + d];
            t1 += hi * whhT[i * 193 + 64 + d];
            t2 += hi * whhT[i * 193 + 128 + d];
        }
        float r = sigmoidf_(s0 + t0);
        float z = sigmoidf_(s1 + t1);
        float nn = tanhf(s2 + r * t2);
        float hn = (1.0f - z) * nn + z * ho[ln][d];
        out[(size_t)n * 64 + d] = hn;
        outT[(size_t)d * NNODES + n] = hn;
        __syncthreads();
    }
}

// Set2Set LSTM step (1 block). iter>0: q_star tail = r/S from prev attention.
__global__ __launch_bounds__(256) void k_lstm(const float* __restrict__ wih,
                                              const float* __restrict__ whh,
                                              const float* __restrict__ bih,
                                              const float* __restrict__ bhh,
                                              float* __restrict__ hl,
                                              float* __restrict__ cl,
                                              float* __restrict__ r_vec,
                                              float* __restrict__ S,
                                              int iter) {
    __shared__ float qs[128];
    __shared__ float gs[256];
    int tid = threadIdx.x;
    if (tid < 64) qs[tid] = hl[tid];
    else if (tid < 128) qs[tid] = (iter > 0) ? r_vec[tid - 64] / S[0] : 0.0f;
    __syncthreads();
    float g = bih[tid] + bhh[tid];
    for (int k = 0; k < 128; ++k) g += qs[k] * wih[tid * 128 + k];
    for (int k = 0; k < 64; ++k) g += qs[k] * whh[tid * 64 + k];
    gs[tid] = g;
    __syncthreads();
    if (tid < 64) {
        float ig = sigmoidf_(gs[tid]);
        float fg = sigmoidf_(gs[64 + tid]);
        float gg = tanhf(gs[128 + tid]);
        float og = sigmoidf_(gs[192 + tid]);
        float c = fg * cl[tid] + ig * gg;
        cl[tid] = c;
        hl[tid] = og * tanhf(c);
        r_vec[tid] = 0.0f;  // reset for upcoming attention pass
        if (tid == 0) S[0] = 0.0f;
    }
}

// attention logits + exp + global sum (no max-sub: logits bounded far below 88)
__global__ __launch_bounds__(256) void k_att1(const float* __restrict__ out,
                                              const float* __restrict__ q,
                                              float* __restrict__ e_att,
                                              float* __restrict__ S) {
    __shared__ float qs[64];
    __shared__ float red[256];
    int tid = threadIdx.x;
    if (tid < 64) qs[tid] = q[tid];
    __syncthreads();
    int n = blockIdx.x * 256 + tid;
    float w = 0.0f;
    if (n < NNODES) {
        const float4* row = reinterpret_cast<const float4*>(out + (size_t)n * 64);
        const float4* qv = reinterpret_cast<const float4*>(qs);
        float e = 0.0f;
#pragma unroll
        for (int k = 0; k < 16; ++k) {
            float4 a = row[k], b = qv[k];
            e += a.x * b.x + a.y * b.y + a.z * b.z + a.w * b.w;
        }
        w = expf(e);
        e_att[n] = w;
    }
    red[tid] = w;
    __syncthreads();
    for (int s = 128; s > 0; s >>= 1) {
        if (tid < s) red[tid] += red[tid + s];
        __syncthreads();
    }
    if (tid == 0) atomicAdd(S, red[0]);
}

// weighted readout: r_vec[d] += sum_n e_att[n]*out[n,d]  (divide by S deferred)
__global__ __launch_bounds__(64) void k_att2(const float* __restrict__ out,
                                             const float* __restrict__ e_att,
                                             float* __restrict__ r_vec) {
    const int d = threadIdx.x;
    const int start = blockIdx.x * 100;
    const int end = (start + 100 < NNODES) ? start + 100 : NNODES;
    float acc = 0.0f;
    for (int n = start; n < end; ++n) acc += e_att[n] * out[(size_t)n * 64 + d];
    atomicAdd(&r_vec[d], acc);
}

__global__ __launch_bounds__(128) void k_out(const float* __restrict__ hl,
                                             const float* __restrict__ r_vec,
                                             const float* __restrict__ S,
                                             const float* __restrict__ lin1_w,
                                             const float* __restrict__ lin1_b,
                                             const float* __restrict__ lin3_w,
                                             const float* __restrict__ lin3_b,
                                             float* __restrict__ dout) {
    __shared__ float qs[128];
    __shared__ float hs[64];
    int tid = threadIdx.x;
    qs[tid] = (tid < 64) ? hl[tid] : r_vec[tid - 64] / S[0];
    __syncthreads();
    if (tid < 64) {
        float a = lin1_b[tid];
        for (int k = 0; k < 128; ++k) a += qs[k] * lin1_w[tid * 128 + k];
        hs[tid] = fmaxf(a, 0.0f);
    }
    __syncthreads();
    if (tid == 0) {
        float a = lin3_b[0];
        for (int k = 0; k < 64; ++k) a += hs[k] * lin3_w[k];
        dout[0] = a;
    }
}

extern "C" void kernel_launch(void* const* d_in, const int* in_sizes, int n_in,
                              void* d_out, int out_size, void* d_ws, size_t ws_size,
                              hipStream_t stream) {
    const float* x         = (const float*)d_in[0];
    const float* edge_attr = (const float*)d_in[1];
    const int*   ei        = (const int*)d_in[2];
    const float* lin0_w    = (const float*)d_in[4];
    const float* lin0_b    = (const float*)d_in[5];
    const float* em1_w     = (const float*)d_in[6];
    const float* em1_b     = (const float*)d_in[7];
    const float* em2_w     = (const float*)d_in[8];
    const float* em2_b     = (const float*)d_in[9];
    const float* root_w    = (const float*)d_in[10];
    const float* conv_b    = (const float*)d_in[11];
    const float* gru_wih   = (const float*)d_in[12];
    const float* gru_whh   = (const float*)d_in[13];
    const float* gru_bih   = (const float*)d_in[14];
    const float* gru_bhh   = (const float*)d_in[15];
    const float* lstm_wih  = (const float*)d_in[16];
    const float* lstm_whh  = (const float*)d_in[17];
    const float* lstm_bih  = (const float*)d_in[18];
    const float* lstm_bhh  = (const float*)d_in[19];
    const float* lin1_w    = (const float*)d_in[20];
    const float* lin1_b    = (const float*)d_in[21];
    const float* lin3_w    = (const float*)d_in[22];
    const float* lin3_b    = (const float*)d_in[23];

    float* ws = (float*)d_ws;
    size_t off = 0;
    float* h1    = ws + off; off += (size_t)NEDGES * 64;   // 2,560,000
    float* W2    = ws + off; off += (size_t)64 * MC;       //   266,240
    float* outb  = ws + off; off += (size_t)NNODES * 64;   //   640,000
    float* outT  = ws + off; off += (size_t)NNODES * 64;   //   640,000
    float* agg   = ws + off; off += (size_t)NNODES * 64;   //   640,000
    float* deg   = ws + off; off += NNODES;
    float* invd  = ws + off; off += NNODES;
    float* e_att = ws + off; off += NNODES;
    float* r_vec = ws + off; off += 64;  // contiguous s2s state: r_vec, hl, cl, S
    float* hl    = ws + off; off += 64;
    float* cl    = ws + off; off += 64;
    float* S     = ws + off; off += 1;
    off = (off + 15) & ~((size_t)15);
    float* M     = ws + off; off += (size_t)NNODES * MC;   // 41,600,000 (~186 MB total)

    k_node_init<<<2500, 256, 0, stream>>>(x, lin0_w, lin0_b, outb, outT);
    k_h1<<<10000, 256, 0, stream>>>(edge_attr, em1_w, em1_b, h1);
    k_w2<<<(64 * MC + 255) / 256, 256, 0, stream>>>(em2_w, em2_b, W2);
    k_zero<<<40, 256, 0, stream>>>(deg, NNODES);
    k_deg<<<(NEDGES + 255) / 256, 256, 0, stream>>>(ei, deg);
    k_invdeg<<<40, 256, 0, stream>>>(deg, invd);

    for (int t = 0; t < 6; ++t) {
        k_zero<<<2500, 256, 0, stream>>>(agg, (size_t)NNODES * 64);
        k_gemm<<<dim3(65, 79), 256, 0, stream>>>(outT, W2, M);
        k_msg<<<NEDGES / 4, 256, 0, stream>>>(M, h1, ei, agg);
        k_node<<<256, 256, 0, stream>>>(agg, invd, root_w, conv_b, gru_wih, gru_whh,
                                        gru_bih, gru_bhh, outb, outT);
    }

    k_zero<<<1, 256, 0, stream>>>(r_vec, 64 + 64 + 64 + 1);  // r_vec, hl, cl, S
    for (int it = 0; it < 6; ++it) {
        k_lstm<<<1, 256, 0, stream>>>(lstm_wih, lstm_whh, lstm_bih, lstm_bhh, hl, cl, r_vec, S, it);
        k_att1<<<40, 256, 0, stream>>>(outb, hl, e_att, S);
        k_att2<<<100, 64, 0, stream>>>(outb, e_att, r_vec);
    }
    k_out<<<1, 128, 0, stream>>>(hl, r_vec, S, lin1_w, lin1_b, lin3_w, lin3_b, (float*)d_out);
}

// Round 3
// 1488.448 us; speedup vs baseline: 2.2540x; 1.1876x over previous
//
#include <hip/hip_runtime.h>
#include <math.h>

#define NNODES 10000
#define NEDGES 40000
#define DIM 64
#define MC 4160  // 4096 h1-contraction cols + 64 bias cols

__device__ __forceinline__ float sigmoidf_(float x) { return 1.0f / (1.0f + expf(-x)); }

// out0 = relu(x @ lin0_w.T + lin0_b)   [N,64] ; also writes transposed copy
__global__ __launch_bounds__(256) void k_node_init(const float* __restrict__ x,
                                                   const float* __restrict__ w,
                                                   const float* __restrict__ b,
                                                   float* __restrict__ out,
                                                   float* __restrict__ outT) {
    int idx = blockIdx.x * 256 + threadIdx.x;
    if (idx >= NNODES * 64) return;
    int n = idx >> 6, d = idx & 63;
    float a = b[d];
    a += x[n * 3 + 0] * w[d * 3 + 0];
    a += x[n * 3 + 1] * w[d * 3 + 1];
    a += x[n * 3 + 2] * w[d * 3 + 2];
    float v = fmaxf(a, 0.0f);
    out[idx] = v;
    outT[(size_t)d * NNODES + n] = v;
}

// h1 = relu(edge_attr @ em1_w.T + em1_b), written at src-sorted position
__global__ __launch_bounds__(256) void k_h1(const float* __restrict__ ea,
                                            const float* __restrict__ w,
                                            const float* __restrict__ b,
                                            const int* __restrict__ sortpos,
                                            float* __restrict__ h1s) {
    int idx = blockIdx.x * 256 + threadIdx.x;
    if (idx >= NEDGES * 64) return;
    int e = idx >> 6, d = idx & 63;
    float a = b[d];
#pragma unroll
    for (int j = 0; j < 7; ++j) a += ea[e * 7 + j] * w[d * 7 + j];
    h1s[(size_t)sortpos[e] * 64 + d] = fmaxf(a, 0.0f);
}

// W2[i, o*64+k] = em2_w[(i*64+o)*64 + k];  W2[i, 4096+o] = em2_b[i*64+o]
__global__ __launch_bounds__(256) void k_w2(const float* __restrict__ em2_w,
                                            const float* __restrict__ em2_b,
                                            float* __restrict__ W2) {
    int idx = blockIdx.x * 256 + threadIdx.x;
    if (idx >= 64 * MC) return;
    int i = idx / MC, c = idx % MC;
    float v;
    if (c < 4096) {
        int o = c >> 6, k = c & 63;
        v = em2_w[((size_t)(i * 64 + o)) * 64 + k];
    } else {
        v = em2_b[i * 64 + (c - 4096)];
    }
    W2[idx] = v;
}

__global__ __launch_bounds__(256) void k_zero(float* __restrict__ p, size_t n) {
    size_t i = (size_t)blockIdx.x * 256 + threadIdx.x;
    if (i < n) p[i] = 0.0f;
}

// src histogram (for CSR sort) + dst degree (for mean)
__global__ __launch_bounds__(256) void k_hist(const int* __restrict__ ei,
                                              int* __restrict__ counts,
                                              float* __restrict__ deg) {
    int e = blockIdx.x * 256 + threadIdx.x;
    if (e < NEDGES) {
        atomicAdd(&counts[ei[e]], 1);
        atomicAdd(&deg[ei[NEDGES + e]], 1.0f);
    }
}

// single-block exclusive scan over counts -> row_start[0..NNODES] and cursor copy
__global__ __launch_bounds__(256) void k_scan(const int* __restrict__ counts,
                                              int* __restrict__ row_start,
                                              int* __restrict__ cursor) {
    __shared__ int buf[256];
    const int tid = threadIdx.x;
    int base = 0;
    for (int c0 = 0; c0 < NNODES; c0 += 256) {
        int i = c0 + tid;
        int v = (i < NNODES) ? counts[i] : 0;
        buf[tid] = v;
        __syncthreads();
        for (int off = 1; off < 256; off <<= 1) {
            int t = (tid >= off) ? buf[tid - off] : 0;
            __syncthreads();
            buf[tid] += t;
            __syncthreads();
        }
        int incl = buf[tid];
        int excl = incl - v;
        if (i < NNODES) {
            int rs = base + excl;
            row_start[i] = rs;
            cursor[i] = rs;
        }
        base += buf[255];
        __syncthreads();
    }
    if (tid == 0) row_start[NNODES] = base;
}

__global__ __launch_bounds__(256) void k_scatter(const int* __restrict__ ei,
                                                 int* __restrict__ cursor,
                                                 int* __restrict__ sortpos,
                                                 int* __restrict__ dst_s) {
    int e = blockIdx.x * 256 + threadIdx.x;
    if (e < NEDGES) {
        int s = ei[e];
        int pos = atomicAdd(&cursor[s], 1);
        sortpos[e] = pos;
        dst_s[pos] = ei[NEDGES + e];
    }
}

__global__ __launch_bounds__(256) void k_invdeg(const float* __restrict__ deg, float* __restrict__ inv) {
    int n = blockIdx.x * 256 + threadIdx.x;
    if (n < NNODES) {
        float dg = deg[n];
        inv[n] = dg > 0.0f ? 1.0f / dg : 0.0f;
    }
}

// M[N, MC] = outT^T @ W2.  AT = outT [64][N] (k-major), B = W2 [64][MC].
// 128 rows x 64 cols per block; 256 threads; 8x4 per thread.
__global__ __launch_bounds__(256) void k_gemm(const float* __restrict__ AT,
                                              const float* __restrict__ B,
                                              float* __restrict__ C) {
    __shared__ float As[64][136];  // [k][row], pad 8
    __shared__ float Bs[64][68];   // [k][col], pad 4
    const int tid = threadIdx.x;
    const int col0 = blockIdx.x * 64;
    const int row0 = blockIdx.y * 128;
#pragma unroll
    for (int j = 0; j < 8; ++j) {
        int idx = tid + 256 * j;       // 0..2047
        int k = idx >> 5;              // 0..63
        int r4 = (idx & 31) * 4;       // 0..124
        int r = row0 + r4;
        float4 v;
        if (r + 3 < NNODES) {
            v = *reinterpret_cast<const float4*>(&AT[(size_t)k * NNODES + r]);
        } else {
            v.x = (r + 0 < NNODES) ? AT[(size_t)k * NNODES + r + 0] : 0.0f;
            v.y = (r + 1 < NNODES) ? AT[(size_t)k * NNODES + r + 1] : 0.0f;
            v.z = (r + 2 < NNODES) ? AT[(size_t)k * NNODES + r + 2] : 0.0f;
            v.w = 0.0f;
        }
        *reinterpret_cast<float4*>(&As[k][r4]) = v;
    }
#pragma unroll
    for (int j = 0; j < 4; ++j) {
        int idx = tid + 256 * j;       // 0..1023
        int k = idx >> 4;              // 0..63
        int c4 = (idx & 15) * 4;       // 0..60
        float4 v = *reinterpret_cast<const float4*>(&B[(size_t)k * MC + col0 + c4]);
        *reinterpret_cast<float4*>(&Bs[k][c4]) = v;
    }
    __syncthreads();
    const int tx = tid & 15, ty = tid >> 4;
    const int r0 = ty * 8, c0 = tx * 4;
    float acc[8][4];
#pragma unroll
    for (int i = 0; i < 8; ++i)
#pragma unroll
        for (int j = 0; j < 4; ++j) acc[i][j] = 0.0f;
#pragma unroll 4
    for (int k = 0; k < 64; ++k) {
        float4 b4 = *reinterpret_cast<const float4*>(&Bs[k][c0]);
        float4 a0 = *reinterpret_cast<const float4*>(&As[k][r0]);
        float4 a1 = *reinterpret_cast<const float4*>(&As[k][r0 + 4]);
        float a[8] = {a0.x, a0.y, a0.z, a0.w, a1.x, a1.y, a1.z, a1.w};
        float b[4] = {b4.x, b4.y, b4.z, b4.w};
#pragma unroll
        for (int i = 0; i < 8; ++i)
#pragma unroll
            for (int j = 0; j < 4; ++j) acc[i][j] += a[i] * b[j];
    }
#pragma unroll
    for (int i = 0; i < 8; ++i) {
        int r = row0 + r0 + i;
        if (r < NNODES) {
            *reinterpret_cast<float4*>(&C[(size_t)r * MC + col0 + c0]) =
                make_float4(acc[i][0], acc[i][1], acc[i][2], acc[i][3]);
        }
    }
}

// src-grouped message: one wave per source node. M row loaded ONCE into registers,
// reused across the node's edges; h1 read uniform-address (L1 broadcast).
__global__ __launch_bounds__(256) void k_msg(const float* __restrict__ M,
                                             const float* __restrict__ h1s,
                                             const int* __restrict__ row_start,
                                             const int* __restrict__ dst_s,
                                             float* __restrict__ agg) {
    const int w = threadIdx.x >> 6;
    const int o = threadIdx.x & 63;
    const int s = blockIdx.x * 4 + w;
    const int e0 = row_start[s];
    const int e1 = row_start[s + 1];
    if (e0 == e1) return;
    const float* mrow = M + (size_t)s * MC;
    const float4* mv = reinterpret_cast<const float4*>(mrow + o * 64);
    float4 m[16];
#pragma unroll
    for (int k = 0; k < 16; ++k) m[k] = mv[k];
    const float bias = mrow[4096 + o];
    for (int e = e0; e < e1; ++e) {
        const float4* hv = reinterpret_cast<const float4*>(h1s + (size_t)e * 64);
        float acc = bias;
#pragma unroll
        for (int k = 0; k < 16; ++k) {
            float4 h4 = hv[k];
            acc += m[k].x * h4.x + m[k].y * h4.y + m[k].z * h4.z + m[k].w * h4.w;
        }
        atomicAdd(&agg[(size_t)dst_s[e] * 64 + o], acc);
    }
}

// fused conv-epilogue + GRU. Grid-stride over 4-node tiles; weights staged ONCE per block.
__global__ __launch_bounds__(256) void k_node(const float* __restrict__ agg,
                                              const float* __restrict__ invdeg,
                                              const float* __restrict__ root_w,
                                              const float* __restrict__ conv_b,
                                              const float* __restrict__ wih,
                                              const float* __restrict__ whh,
                                              const float* __restrict__ bih,
                                              const float* __restrict__ bhh,
                                              float* __restrict__ out,
                                              float* __restrict__ outT) {
    __shared__ float wihT[64 * 193];  // [i][j], padded stride 193
    __shared__ float whhT[64 * 193];
    __shared__ float rws[64][65];     // root_w [i][d]
    __shared__ float ho[4][64];
    __shared__ float ms[4][64];
    const int tid = threadIdx.x;
#pragma unroll
    for (int it = 0; it < 48; ++it) {  // 192*64 / 256
        int idx = tid + 256 * it;
        int j = idx >> 6, i = idx & 63;
        wihT[i * 193 + j] = wih[idx];
        whhT[i * 193 + j] = whh[idx];
    }
#pragma unroll
    for (int it = 0; it < 16; ++it) {  // 64*64 / 256
        int idx = tid + 256 * it;
        rws[idx >> 6][idx & 63] = root_w[idx];
    }
    const int ln = tid >> 6;
    const int d = tid & 63;
    const float cb = conv_b[d];
    const float b0 = bih[d] , bh0 = bhh[d];
    const float b1 = bih[64 + d], bh1 = bhh[64 + d];
    const float b2 = bih[128 + d], bh2 = bhh[128 + d];
    __syncthreads();
    for (int tile = blockIdx.x; tile < NNODES / 4; tile += gridDim.x) {
        const int n = tile * 4 + ln;
        ho[ln][d] = out[(size_t)n * 64 + d];
        __syncthreads();
        float acc = agg[(size_t)n * 64 + d] * invdeg[n] + cb;
#pragma unroll
        for (int i = 0; i < 64; ++i) acc += ho[ln][i] * rws[i][d];
        ms[ln][d] = fmaxf(acc, 0.0f);
        __syncthreads();
        float s0 = b0, s1 = b1, s2 = b2;
        float t0 = bh0, t1 = bh1, t2 = bh2;
#pragma unroll
        for (int i = 0; i < 64; ++i) {
            float mi = ms[ln][i], hi = ho[ln][i];
            s0 += mi * wihT[i * 193 + d];
            s1 += mi * wihT[i * 193 + 64 + d];
            s2 += mi * wihT[i * 193 + 128 + d];
            t0 += hi * whhT[i * 193 + d];
            t1 += hi * whhT[i * 193 + 64 + d];
            t2 += hi * whhT[i * 193 + 128 + d];
        }
        float r = sigmoidf_(s0 + t0);
        float z = sigmoidf_(s1 + t1);
        float nn = tanhf(s2 + r * t2);
        float hn = (1.0f - z) * nn + z * ho[ln][d];
        out[(size_t)n * 64 + d] = hn;
        outT[(size_t)d * NNODES + n] = hn;
        __syncthreads();
    }
}

// Set2Set LSTM step (1 block). iter>0: q_star tail = r/S from prev attention.
__global__ __launch_bounds__(256) void k_lstm(const float* __restrict__ wih,
                                              const float* __restrict__ whh,
                                              const float* __restrict__ bih,
                                              const float* __restrict__ bhh,
                                              float* __restrict__ hl,
                                              float* __restrict__ cl,
                                              float* __restrict__ r_vec,
                                              float* __restrict__ S,
                                              int iter) {
    __shared__ float qs[128];
    __shared__ float gs[256];
    int tid = threadIdx.x;
    if (tid < 64) qs[tid] = hl[tid];
    else if (tid < 128) qs[tid] = (iter > 0) ? r_vec[tid - 64] / S[0] : 0.0f;
    __syncthreads();
    float g = bih[tid] + bhh[tid];
    for (int k = 0; k < 128; ++k) g += qs[k] * wih[tid * 128 + k];
    for (int k = 0; k < 64; ++k) g += qs[k] * whh[tid * 64 + k];
    gs[tid] = g;
    __syncthreads();
    if (tid < 64) {
        float ig = sigmoidf_(gs[tid]);
        float fg = sigmoidf_(gs[64 + tid]);
        float gg = tanhf(gs[128 + tid]);
        float og = sigmoidf_(gs[192 + tid]);
        float c = fg * cl[tid] + ig * gg;
        cl[tid] = c;
        hl[tid] = og * tanhf(c);
        r_vec[tid] = 0.0f;  // reset for upcoming attention pass
        if (tid == 0) S[0] = 0.0f;
    }
}

// attention logits + exp + global sum (no max-sub: logits bounded far below 88)
__global__ __launch_bounds__(256) void k_att1(const float* __restrict__ out,
                                              const float* __restrict__ q,
                                              float* __restrict__ e_att,
                                              float* __restrict__ S) {
    __shared__ float qs[64];
    __shared__ float red[256];
    int tid = threadIdx.x;
    if (tid < 64) qs[tid] = q[tid];
    __syncthreads();
    int n = blockIdx.x * 256 + tid;
    float w = 0.0f;
    if (n < NNODES) {
        const float4* row = reinterpret_cast<const float4*>(out + (size_t)n * 64);
        const float4* qv = reinterpret_cast<const float4*>(qs);
        float e = 0.0f;
#pragma unroll
        for (int k = 0; k < 16; ++k) {
            float4 a = row[k], b = qv[k];
            e += a.x * b.x + a.y * b.y + a.z * b.z + a.w * b.w;
        }
        w = expf(e);
        e_att[n] = w;
    }
    red[tid] = w;
    __syncthreads();
    for (int s = 128; s > 0; s >>= 1) {
        if (tid < s) red[tid] += red[tid + s];
        __syncthreads();
    }
    if (tid == 0) atomicAdd(S, red[0]);
}

// weighted readout: r_vec[d] += sum_n e_att[n]*out[n,d]  (divide by S deferred)
__global__ __launch_bounds__(64) void k_att2(const float* __restrict__ out,
                                             const float* __restrict__ e_att,
                                             float* __restrict__ r_vec) {
    const int d = threadIdx.x;
    const int start = blockIdx.x * 100;
    const int end = (start + 100 < NNODES) ? start + 100 : NNODES;
    float acc = 0.0f;
    for (int n = start; n < end; ++n) acc += e_att[n] * out[(size_t)n * 64 + d];
    atomicAdd(&r_vec[d], acc);
}

__global__ __launch_bounds__(128) void k_out(const float* __restrict__ hl,
                                             const float* __restrict__ r_vec,
                                             const float* __restrict__ S,
                                             const float* __restrict__ lin1_w,
                                             const float* __restrict__ lin1_b,
                                             const float* __restrict__ lin3_w,
                                             const float* __restrict__ lin3_b,
                                             float* __restrict__ dout) {
    __shared__ float qs[128];
    __shared__ float hs[64];
    int tid = threadIdx.x;
    qs[tid] = (tid < 64) ? hl[tid] : r_vec[tid - 64] / S[0];
    __syncthreads();
    if (tid < 64) {
        float a = lin1_b[tid];
        for (int k = 0; k < 128; ++k) a += qs[k] * lin1_w[tid * 128 + k];
        hs[tid] = fmaxf(a, 0.0f);
    }
    __syncthreads();
    if (tid == 0) {
        float a = lin3_b[0];
        for (int k = 0; k < 64; ++k) a += hs[k] * lin3_w[k];
        dout[0] = a;
    }
}

extern "C" void kernel_launch(void* const* d_in, const int* in_sizes, int n_in,
                              void* d_out, int out_size, void* d_ws, size_t ws_size,
                              hipStream_t stream) {
    const float* x         = (const float*)d_in[0];
    const float* edge_attr = (const float*)d_in[1];
    const int*   ei        = (const int*)d_in[2];
    const float* lin0_w    = (const float*)d_in[4];
    const float* lin0_b    = (const float*)d_in[5];
    const float* em1_w     = (const float*)d_in[6];
    const float* em1_b     = (const float*)d_in[7];
    const float* em2_w     = (const float*)d_in[8];
    const float* em2_b     = (const float*)d_in[9];
    const float* root_w    = (const float*)d_in[10];
    const float* conv_b    = (const float*)d_in[11];
    const float* gru_wih   = (const float*)d_in[12];
    const float* gru_whh   = (const float*)d_in[13];
    const float* gru_bih   = (const float*)d_in[14];
    const float* gru_bhh   = (const float*)d_in[15];
    const float* lstm_wih  = (const float*)d_in[16];
    const float* lstm_whh  = (const float*)d_in[17];
    const float* lstm_bih  = (const float*)d_in[18];
    const float* lstm_bhh  = (const float*)d_in[19];
    const float* lin1_w    = (const float*)d_in[20];
    const float* lin1_b    = (const float*)d_in[21];
    const float* lin3_w    = (const float*)d_in[22];
    const float* lin3_b    = (const float*)d_in[23];

    float* ws = (float*)d_ws;
    size_t off = 0;
    float* h1s   = ws + off; off += (size_t)NEDGES * 64;   // 2,560,000
    float* W2    = ws + off; off += (size_t)64 * MC;       //   266,240
    float* outb  = ws + off; off += (size_t)NNODES * 64;
    float* outT  = ws + off; off += (size_t)NNODES * 64;
    float* agg   = ws + off; off += (size_t)NNODES * 64;
    float* deg   = ws + off; off += NNODES;   // deg, counts, cursor contiguous (one zero)
    int*   counts    = (int*)(ws + off); off += NNODES;
    int*   cursor    = (int*)(ws + off); off += NNODES;
    int*   row_start = (int*)(ws + off); off += NNODES + 1;
    int*   sortpos   = (int*)(ws + off); off += NEDGES;
    int*   dst_s     = (int*)(ws + off); off += NEDGES;
    float* invd  = ws + off; off += NNODES;
    float* e_att = ws + off; off += NNODES;
    float* r_vec = ws + off; off += 64;  // contiguous s2s state: r_vec, hl, cl, S
    float* hl    = ws + off; off += 64;
    float* cl    = ws + off; off += 64;
    float* S     = ws + off; off += 1;
    off = (off + 15) & ~((size_t)15);
    float* M     = ws + off; off += (size_t)NNODES * MC;   // 41,600,000 (~186 MB total)

    k_node_init<<<2500, 256, 0, stream>>>(x, lin0_w, lin0_b, outb, outT);
    k_w2<<<(64 * MC + 255) / 256, 256, 0, stream>>>(em2_w, em2_b, W2);
    k_zero<<<(3 * NNODES + 255) / 256, 256, 0, stream>>>(deg, 3 * NNODES);  // deg+counts+cursor
    k_hist<<<(NEDGES + 255) / 256, 256, 0, stream>>>(ei, counts, deg);
    k_scan<<<1, 256, 0, stream>>>(counts, row_start, cursor);
    k_scatter<<<(NEDGES + 255) / 256, 256, 0, stream>>>(ei, cursor, sortpos, dst_s);
    k_invdeg<<<(NNODES + 255) / 256, 256, 0, stream>>>(deg, invd);
    k_h1<<<10000, 256, 0, stream>>>(edge_attr, em1_w, em1_b, sortpos, h1s);

    for (int t = 0; t < 6; ++t) {
        k_zero<<<2500, 256, 0, stream>>>(agg, (size_t)NNODES * 64);
        k_gemm<<<dim3(65, 79), 256, 0, stream>>>(outT, W2, M);
        k_msg<<<2500, 256, 0, stream>>>(M, h1s, row_start, dst_s, agg);
        k_node<<<256, 256, 0, stream>>>(agg, invd, root_w, conv_b, gru_wih, gru_whh,
                                        gru_bih, gru_bhh, outb, outT);
    }

    k_zero<<<1, 256, 0, stream>>>(r_vec, 64 + 64 + 64 + 1);  // r_vec, hl, cl, S
    for (int it = 0; it < 6; ++it) {
        k_lstm<<<1, 256, 0, stream>>>(lstm_wih, lstm_whh, lstm_bih, lstm_bhh, hl, cl, r_vec, S, it);
        k_att1<<<40, 256, 0, stream>>>(outb, hl, e_att, S);
        k_att2<<<100, 64, 0, stream>>>(outb, e_att, r_vec);
    }
    k_out<<<1, 128, 0, stream>>>(hl, r_vec, S, lin1_w, lin1_b, lin3_w, lin3_b, (float*)d_out);
}